// Round 4
// baseline (415.654 us; speedup 1.0000x reference)
//
#include <hip/hip_runtime.h>
#include <hip/hip_bf16.h>

#define VOCAB   50000
#define SEQ     200
#define NCHUNK  4
#define CHUNK   (VOCAB / NCHUNK)   // 12500 buckets per block
#define CDW     (CHUNK / 4)        // 3125 packed-u8 count dwords
#define CDW_PAD 3136               // pad to x8 dwords so uint4 zeroing covers all

typedef float v4f __attribute__((ext_vector_type(4)));   // native vector type
typedef unsigned v4u __attribute__((ext_vector_type(4)));

// One block per (row, vocab-chunk). 12.5 KB LDS -> occupancy capped by
// threads (8 blocks/CU = 32 waves/CU = 100%), not LDS (was 3 blocks/CU at
// 50 KB). Counts packed 4x u8 per dword; row total = 200 < 256 so no byte
// overflow and the packed atomicAdd can't carry across byte lanes.
// Each output line is written exactly once, nontemporal (streaming).
__global__ __launch_bounds__(256) void MultihotEmbedding_16458314678493_kernel(
    const int* __restrict__ x, float* __restrict__ out) {
  __shared__ unsigned cnt[CDW_PAD];

  // Phase 1: zero LDS histogram (784 v4u / 256 threads ~= 4 iters).
  v4u* __restrict__ c4 = (v4u*)cnt;
  const v4u z = {0u, 0u, 0u, 0u};
  for (int i = threadIdx.x; i < CDW_PAD / 4; i += 256) c4[i] = z;
  __syncthreads();

  const int row = blockIdx.x >> 2;        // NCHUNK == 4
  const int lo  = (blockIdx.x & 3) * CHUNK;
  const int* __restrict__ xr = x + row * SEQ;

  // Phase 2: scan the row's 200 indices, count those in [lo, lo+CHUNK).
  for (int t = threadIdx.x; t < SEQ; t += 256) {
    const int idx = xr[t] - lo;
    if ((unsigned)idx < (unsigned)CHUNK)
      atomicAdd(&cnt[idx >> 2], 1u << ((idx & 3) * 8));
  }
  __syncthreads();

  // Phase 3: 1 ds_read_b32 (4 counts) -> v_cvt_f32_ubyte0..3 -> 16B nt store.
  // Chunk byte offset = lo*4 = 50000B, multiple of 16 -> 16B aligned.
  v4f* __restrict__ o4 = (v4f*)(out + (size_t)row * VOCAB + lo);
  for (int i = threadIdx.x; i < CDW; i += 256) {
    const unsigned u = cnt[i];
    v4f v;
    v.x = (float)(u & 0xffu);
    v.y = (float)((u >> 8) & 0xffu);
    v.z = (float)((u >> 16) & 0xffu);
    v.w = (float)(u >> 24);
    __builtin_nontemporal_store(v, &o4[i]);
  }
}

extern "C" void kernel_launch(void* const* d_in, const int* in_sizes, int n_in,
                              void* d_out, int out_size, void* d_ws, size_t ws_size,
                              hipStream_t stream) {
  const int* x = (const int*)d_in[0];
  float* out = (float*)d_out;
  const int batch = in_sizes[0] / SEQ;  // 2048
  MultihotEmbedding_16458314678493_kernel<<<batch * NCHUNK, 256, 0, stream>>>(x, out);
}

// Round 5
// 410.783 us; speedup vs baseline: 1.0119x; 1.0119x over previous
//
#include <hip/hip_runtime.h>
#include <hip/hip_bf16.h>

#define VOCAB   50000
#define SEQ     200
#define NCHUNK  4
#define CHUNK   (VOCAB / NCHUNK)   // 12500 buckets per block
#define CDW     (CHUNK / 4)        // 3125 packed-u8 count dwords
#define CDW_PAD 3136               // pad to x4 dwords for uint4 zeroing

typedef float v4f __attribute__((ext_vector_type(4)));
typedef unsigned v4u __attribute__((ext_vector_type(4)));

// One block per (row, vocab-chunk). Structure decouples the 409.6 MB bulk
// output (pure zero-store stream, same shape as the 6.2 TB/s fill kernel)
// from the histogram:
//   P0: load my index (1/thread, SEQ=200<=256) early; zero LDS histogram
//   P1: LDS atomics (histogram) + pure float4 zero-stores over the chunk
//   P2: threads with in-chunk indices overwrite their position with the
//       final count (plain dword store; duplicate indices store identical
//       values -> benign; lines are L2-hot from P1 so partial writes merge).
// Counts packed 4x u8/dword (row total 200 < 256: no overflow/carry).
// LDS 12.25 KB -> 8 blocks/CU (threads-capped), 32 waves/CU.
__global__ __launch_bounds__(256) void MultihotEmbedding_16458314678493_kernel(
    const int* __restrict__ x, float* __restrict__ out) {
  __shared__ unsigned cnt[CDW_PAD];

  const int row = blockIdx.x >> 2;        // NCHUNK == 4
  const int lo  = (blockIdx.x & 3) * CHUNK;

  // P0: early index load (global latency overlaps LDS zeroing below).
  int myidx = CHUNK;  // out of range
  if (threadIdx.x < SEQ) myidx = x[row * SEQ + threadIdx.x] - lo;

  v4u* __restrict__ c4 = (v4u*)cnt;
  const v4u z4 = {0u, 0u, 0u, 0u};
  for (int i = threadIdx.x; i < CDW_PAD / 4; i += 256) c4[i] = z4;
  __syncthreads();

  // P1: histogram atomic (<=1 per thread) + bulk zero-store stream.
  if ((unsigned)myidx < (unsigned)CHUNK)
    atomicAdd(&cnt[myidx >> 2], 1u << ((myidx & 3) * 8));

  float* __restrict__ orow = out + (size_t)row * VOCAB + lo;
  v4f* __restrict__ o4 = (v4f*)orow;      // 16B aligned: lo*4 % 16 == 0
  const v4f zf = {0.f, 0.f, 0.f, 0.f};
  #pragma unroll 4
  for (int i = threadIdx.x; i < CDW; i += 256) o4[i] = zf;
  __syncthreads();

  // P2: scatter final counts over the zeros (L2-resident lines).
  if ((unsigned)myidx < (unsigned)CHUNK) {
    const unsigned c = (cnt[myidx >> 2] >> ((myidx & 3) * 8)) & 0xffu;
    orow[myidx] = (float)c;
  }
}

extern "C" void kernel_launch(void* const* d_in, const int* in_sizes, int n_in,
                              void* d_out, int out_size, void* d_ws, size_t ws_size,
                              hipStream_t stream) {
  const int* x = (const int*)d_in[0];
  float* out = (float*)d_out;
  const int batch = in_sizes[0] / SEQ;  // 2048
  MultihotEmbedding_16458314678493_kernel<<<batch * NCHUNK, 256, 0, stream>>>(x, out);
}